// Round 12
// baseline (346.318 us; speedup 1.0000x reference)
//
#include <hip/hip_runtime.h>
#include <hip/hip_bf16.h>

// Problem constants: B=2, N=2048, C=768, H=12, HD=64
typedef __bf16 bf8 __attribute__((ext_vector_type(8)));
typedef float f4 __attribute__((ext_vector_type(4)));

__device__ __forceinline__ unsigned short f2b(float f) {
  union { __hip_bfloat16 h; unsigned short u; } cv;
  cv.h = __float2bfloat16(f);
  return cv.u;
}

__device__ __forceinline__ float b2f(unsigned short u) {
  union { unsigned int u; float f; } cv;
  cv.u = ((unsigned int)u) << 16;
  return cv.f;
}

__device__ __forceinline__ f4 mfma16(bf8 a, bf8 b, f4 c) {
  return __builtin_amdgcn_mfma_f32_16x16x32_bf16(a, b, c, 0, 0, 0);
}

// async global->LDS staging, 16B per lane; lds base must be wave-uniform
__device__ __forceinline__ void stage16(const unsigned short* g, unsigned short* lbase, int lane) {
#if __has_builtin(__builtin_amdgcn_global_load_lds)
  __builtin_amdgcn_global_load_lds((const __attribute__((address_space(1))) void*)g,
                                   (__attribute__((address_space(3))) void*)lbase, 16, 0, 0);
#else
  *(bf8*)((char*)lbase + lane * 16) = *(const bf8*)g;
#endif
}

// ---------------- merged: x->bf16 + mask/bias prep (bid<3097) | weight transposes ------
__global__ void k_prept(const float* __restrict__ x, unsigned short* __restrict__ xb,
                        const void* __restrict__ mraw, const float* __restrict__ bq,
                        const float* __restrict__ bkv, float* __restrict__ maskbias,
                        float* __restrict__ biasc,
                        const float* __restrict__ Wq, const float* __restrict__ Wkv,
                        const float* __restrict__ Wp, unsigned short* __restrict__ Wct,
                        unsigned short* __restrict__ Wpt) {
  __shared__ float tile[32][33];
  const int bid = blockIdx.x;
  if (bid < 3072) {
    size_t t = (size_t)bid * 256 + threadIdx.x;
    float4 v = *(const float4*)(x + t * 4);
    ushort4 o;
    o.x = f2b(v.x); o.y = f2b(v.y); o.z = f2b(v.z); o.w = f2b(v.w);
    *(ushort4*)(xb + t * 4) = o;
    return;
  }
  if (bid < 3097) {
    int t = (bid - 3072) * 256 + threadIdx.x;
    const unsigned char* pb = (const unsigned char*)mraw;
    const unsigned int* pd = (const unsigned int*)mraw;
    int isfloat = 0, isbyte = 0;
    for (int i = 0; i < 128; ++i) {   // 512 bytes, safe for bool/int32/f32 mask dtypes
      unsigned int d = pd[i];
      if (d == 0x3f800000u) isfloat = 1;
      if ((d & 0xffffff00u) != 0u && d != 0x3f800000u) isbyte = 1;
    }
    if (t < 4096) {
      int v;
      if (isbyte)       v = pb[t];
      else if (isfloat) v = (((const float*)mraw)[t] != 0.0f);
      else              v = ((const int*)mraw)[t];
      maskbias[t] = v ? 0.0f : -1e30f;
    } else if (t < 4096 + 2304) {
      int j = t - 4096;
      biasc[j] = (j < 768) ? bq[j] : bkv[j - 768];
    }
    return;
  }
  // transpose3: fp32 [R][Cc] -> bf16 [Cc][R]
  int id = bid - 3097;
  int bx = id % 96, by = id / 96;
  const float* in; unsigned short* out; int Cc, bxl;
  if (bx < 24)      { in = Wq;  out = Wct;                         Cc = 768;  bxl = bx; }
  else if (bx < 72) { in = Wkv; out = Wct + (size_t)768 * 768;     Cc = 1536; bxl = bx - 24; }
  else              { in = Wp;  out = Wpt;                         Cc = 768;  bxl = bx - 72; }
  const int R = 768;
  int c0 = bxl * 32, r0 = by * 32;
  int tx = threadIdx.x & 31, ty = threadIdx.x >> 5;
  for (int j = 0; j < 32; j += 8)
    tile[ty + j][tx] = in[(size_t)(r0 + ty + j) * Cc + c0 + tx];
  __syncthreads();
  for (int j = 0; j < 32; j += 8)
    out[(size_t)(c0 + ty + j) * R + r0 + tx] = f2b(tile[tx][ty + j]);
}

// ---------------- bf16 GEMM, reg-direct epilogues, 16KB LDS ----------------
// A = Wt rows (c-dim, blockIdx.x), B = Act rows (n-dim, blockIdx.y).
// MODE 0: c<1536 -> mfma(W,x): lane holds 4 consec hd -> q/k [b][h][n][hd] ushort4.
//         c>=1536 -> mfma(x,W): lane holds 4 consec n  -> vT [b][h][hd][n] ushort4.
// MODE 1: mfma(W,x): lane holds 4 consec out-cols -> float4 (+bias).
// NOTE: h = cb>>6 (and -12 for k). R8's (cb & 767) was WRONG: 768 is not pow2.
template<int MODE>
__global__ __launch_bounds__(256) void k_gemm(
    const unsigned short* __restrict__ Wt,
    const unsigned short* __restrict__ Act,
    const float* __restrict__ bias,
    float* __restrict__ outf,
    unsigned short* __restrict__ qo,
    unsigned short* __restrict__ ko,
    unsigned short* __restrict__ vTo,
    int K)
{
  __shared__ unsigned short As[128 * 32];
  __shared__ unsigned short Bs[128 * 32];
  const int tid = threadIdx.x;
  const int w = tid >> 6, l = tid & 63;
  const int wr = w >> 1, wc = w & 1;
  const int c0 = blockIdx.x * 128, m0 = blockIdx.y * 128;
  const int lrow = l >> 2, lcol = l & 3;
  const int fr = l & 15, fg = l >> 4, fk = fg * 8;
  const bool vpath = (MODE == 0) && (c0 >= 1536);
  f4 acc[4][4] = {};

  for (int k0 = 0; k0 < K; k0 += 32) {
    for (int j = 0; j < 2; ++j) {
      int ra = w * 32 + j * 16;
      stage16(Wt  + (size_t)(c0 + ra + lrow) * K + k0 + lcol * 8, &As[ra * 32], l);
      stage16(Act + (size_t)(m0 + ra + lrow) * K + k0 + lcol * 8, &Bs[ra * 32], l);
    }
    asm volatile("s_waitcnt vmcnt(0)" ::: "memory");
    __syncthreads();
    bf8 fa[4], fb[4];
#pragma unroll
    for (int i = 0; i < 4; ++i) fa[i] = *(const bf8*)&As[(wr * 64 + i * 16 + fr) * 32 + fk];
#pragma unroll
    for (int i = 0; i < 4; ++i) fb[i] = *(const bf8*)&Bs[(wc * 64 + i * 16 + fr) * 32 + fk];
    if (!vpath) {
#pragma unroll
      for (int i = 0; i < 4; ++i)
#pragma unroll
        for (int j2 = 0; j2 < 4; ++j2)
          acc[i][j2] = mfma16(fa[i], fb[j2], acc[i][j2]);   // D rows = c
    } else {
#pragma unroll
      for (int j2 = 0; j2 < 4; ++j2)
#pragma unroll
        for (int i = 0; i < 4; ++i)
          acc[j2][i] = mfma16(fb[j2], fa[i], acc[j2][i]);   // D rows = n
    }
    __syncthreads();
  }

  if (MODE == 1) {
#pragma unroll
    for (int i2 = 0; i2 < 4; ++i2) {
      int cb = c0 + wr * 64 + i2 * 16 + fg * 4;
      float4 bv = *(const float4*)&bias[cb];
#pragma unroll
      for (int j2 = 0; j2 < 4; ++j2) {
        int n = m0 + wc * 64 + j2 * 16 + fr;
        float4 o;
        o.x = acc[i2][j2][0] + bv.x; o.y = acc[i2][j2][1] + bv.y;
        o.z = acc[i2][j2][2] + bv.z; o.w = acc[i2][j2][3] + bv.w;
        *(float4*)(outf + (size_t)n * 768 + cb) = o;
      }
    }
  } else if (!vpath) {
#pragma unroll
    for (int i2 = 0; i2 < 4; ++i2) {
      int cb = c0 + wr * 64 + i2 * 16 + fg * 4;
      float4 bv = *(const float4*)&bias[cb];
      int hd = cb & 63;
      int h = cb >> 6;                        // 0..11 q, 12..23 k
      unsigned short* base = (cb < 768) ? qo : ko;
      if (cb >= 768) h -= 12;
#pragma unroll
      for (int j2 = 0; j2 < 4; ++j2) {
        int n = m0 + wc * 64 + j2 * 16 + fr;
        int b = n >> 11, nn = n & 2047;
        ushort4 pk;
        pk.x = f2b(acc[i2][j2][0] + bv.x); pk.y = f2b(acc[i2][j2][1] + bv.y);
        pk.z = f2b(acc[i2][j2][2] + bv.z); pk.w = f2b(acc[i2][j2][3] + bv.w);
        *(ushort4*)(base + (((size_t)b * 12 + h) * 2048 + nn) * 64 + hd) = pk;
      }
    }
  } else {
#pragma unroll
    for (int j2 = 0; j2 < 4; ++j2) {
      int nb = m0 + wc * 64 + j2 * 16 + fg * 4;
      int b = nb >> 11, nn = nb & 2047;
#pragma unroll
      for (int i2 = 0; i2 < 4; ++i2) {
        int cc = c0 + wr * 64 + i2 * 16 + fr;
        float bvs = bias[cc];
        int c2 = cc - 1536, h = c2 >> 6, hd = c2 & 63;
        ushort4 pk;
        pk.x = f2b(acc[j2][i2][0] + bvs); pk.y = f2b(acc[j2][i2][1] + bvs);
        pk.z = f2b(acc[j2][i2][2] + bvs); pk.w = f2b(acc[j2][i2][3] + bvs);
        *(ushort4*)(vTo + (((size_t)b * 12 + h) * 64 + hd) * 2048 + nn) = pk;
      }
    }
  }
}

// ---------------- P producer: S^T = K·Q^T GEMM, reg-direct exp epilogue ----------------
// grid (16 mt, 16 nt, 24 bh). mfma(K,Q): lane holds 4 consecutive m for fixed n ->
// ushort4 stores to Pws[bh][n][m] (L2 merges 8B segments into lines). Mref=0.
// Lpart[bh][mt*2+wr][n] row-sums via 2 shuffles. 16KB LDS, no epilogue barrier.
__global__ __launch_bounds__(256) void k_pexp(
    const unsigned short* __restrict__ q,
    const unsigned short* __restrict__ kk,
    const float* __restrict__ maskbias,
    unsigned short* __restrict__ Pws,
    float* __restrict__ Lpart)
{
  __shared__ unsigned short As[128 * 32];   // K rows (m)
  __shared__ unsigned short Bs[128 * 32];   // Q rows (n)
  const int tid = threadIdx.x;
  const int w = tid >> 6, l = tid & 63;
  const int wr = w >> 1, wc = w & 1;
  const int mt = blockIdx.x, nt = blockIdx.y, bh = blockIdx.z;
  const int b = bh / 12;
  const int m0 = mt * 128, n0 = nt * 128;
  const int lrow = l >> 2, lcol = l & 3;
  const int fr = l & 15, fg = l >> 4, fk = fg * 8;
  const unsigned short* qh = q + (size_t)bh * 2048 * 64;
  const unsigned short* kh = kk + (size_t)bh * 2048 * 64;
  f4 acc[4][4] = {};

  for (int k0 = 0; k0 < 64; k0 += 32) {
    for (int j = 0; j < 2; ++j) {
      int ra = w * 32 + j * 16;
      stage16(kh + (size_t)(m0 + ra + lrow) * 64 + k0 + lcol * 8, &As[ra * 32], l);
      stage16(qh + (size_t)(n0 + ra + lrow) * 64 + k0 + lcol * 8, &Bs[ra * 32], l);
    }
    asm volatile("s_waitcnt vmcnt(0)" ::: "memory");
    __syncthreads();
    bf8 fa[4], fb[4];
#pragma unroll
    for (int i = 0; i < 4; ++i) fa[i] = *(const bf8*)&As[(wr * 64 + i * 16 + fr) * 32 + fk];
#pragma unroll
    for (int i = 0; i < 4; ++i) fb[i] = *(const bf8*)&Bs[(wc * 64 + i * 16 + fr) * 32 + fk];
#pragma unroll
    for (int mi = 0; mi < 4; ++mi)
#pragma unroll
      for (int nj = 0; nj < 4; ++nj)
        acc[mi][nj] = mfma16(fa[mi], fb[nj], acc[mi][nj]);   // D rows = m, cols = n
    __syncthreads();
  }

  const float scale = 0.125f;
  const float* mbp = maskbias + b * 2048 + m0 + wr * 64;
  float rs[4] = {0.f, 0.f, 0.f, 0.f};
#pragma unroll
  for (int mi = 0; mi < 4; ++mi) {
    float4 mb4 = *(const float4*)&mbp[mi * 16 + fg * 4];
#pragma unroll
    for (int nj = 0; nj < 4; ++nj) {
      int n = n0 + wc * 64 + nj * 16 + fr;
      float p0 = __expf(fmaf(acc[mi][nj][0], scale, mb4.x));
      float p1 = __expf(fmaf(acc[mi][nj][1], scale, mb4.y));
      float p2 = __expf(fmaf(acc[mi][nj][2], scale, mb4.z));
      float p3 = __expf(fmaf(acc[mi][nj][3], scale, mb4.w));
      rs[nj] += p0 + p1 + p2 + p3;
      ushort4 pk;
      pk.x = f2b(p0); pk.y = f2b(p1); pk.z = f2b(p2); pk.w = f2b(p3);
      *(ushort4*)(Pws + ((size_t)bh * 2048 + n) * 2048 + m0 + wr * 64 + mi * 16 + fg * 4) = pk;
    }
  }
#pragma unroll
  for (int nj = 0; nj < 4; ++nj) {
    float r2 = rs[nj];
    r2 += __shfl_xor(r2, 16);
    r2 += __shfl_xor(r2, 32);
    if (fg == 0)
      Lpart[((size_t)bh * 32 + mt * 2 + wr) * 2048 + n0 + wc * 64 + nj * 16 + fr] = r2;
  }
}

// ---------------- reduce 32 L slices -> iL ----------------
__global__ void k_lred(const float* __restrict__ Lpart, float* __restrict__ iLst) {
  int t = blockIdx.x * 256 + threadIdx.x;   // 49152 = 24 bh x 2048 n
  int bh = t >> 11, n = t & 2047;
  float s = 0.0f;
#pragma unroll
  for (int sl = 0; sl < 32; ++sl)
    s += Lpart[((size_t)bh * 32 + sl) * 2048 + n];
  iLst[t] = 1.0f / fmaxf(s, 1e-30f);
}

// ---------------- merged: PV (bid<768) | att writer (else) ----------------
// pv blocks dispatched FIRST -> resident from t=0, MFMA overlaps attw's BW streaming.
__global__ __launch_bounds__(256) void k_attwpv(
    const unsigned short* __restrict__ Pws,
    const float* __restrict__ iLst,
    float* __restrict__ att,
    const unsigned short* __restrict__ vT,
    unsigned short* __restrict__ ao)
{
  __shared__ unsigned short smem[6656];
  const int bid = blockIdx.x;
  const int tid = threadIdx.x;
  const int w = tid >> 6, l = tid & 63;

  if (bid < 768) {
    // ---- PV: O = P @ V, ks=1, iL folded, writes ao bf16 directly ----
    unsigned short* B0 = smem;            // [64*32]
    unsigned short* B1 = smem + 2048;     // [64*32]
    const int bh = bid % 24, nt = bid / 24;
    const int b = bh / 12, h = bh % 12;
    const int n0 = nt * 64;
    const int lr = l >> 2, lc = (l & 3) * 8;
    const int fr = l & 15, fg = l >> 4, fk = fg * 8;
    const unsigned short* Ph = Pws + (size_t)bh * 2048 * 2048
                             + (size_t)(n0 + w * 16 + fr) * 2048 + fk;
    const unsigned short* vh = vT + (size_t)bh * 64 * 2048;
    f4 acc[4] = {};

    for (int k0 = 0; k0 < 2048; k0 += 64) {
      stage16(vh + (size_t)(w * 16 + lr) * 2048 + k0 + lc,      &B0[(w * 16) * 32], l);
      stage16(vh + (size_t)(w * 16 + lr) * 2048 + k0 + 32 + lc, &B1[(w * 16) * 32], l);
      bf8 a0 = *(const bf8*)(Ph + k0);
      bf8 a1 = *(const bf8*)(Ph + k0 + 32);
      asm volatile("s_waitcnt vmcnt(0)" ::: "memory");
      __syncthreads();
#pragma unroll
      for (int j2 = 0; j2 < 4; ++j2) {
        bf8 bv = *(const bf8*)&B0[(j2 * 16 + fr) * 32 + fk];
        acc[j2] = mfma16(a0, bv, acc[j2]);
      }
#pragma unroll
      for (int j2 = 0; j2 < 4; ++j2) {
        bf8 bv = *(const bf8*)&B1[(j2 * 16 + fr) * 32 + fk];
        acc[j2] = mfma16(a1, bv, acc[j2]);
      }
      __syncthreads();
    }

    float il[4];
#pragma unroll
    for (int r = 0; r < 4; ++r)
      il[r] = iLst[(size_t)bh * 2048 + n0 + w * 16 + fg * 4 + r];
#pragma unroll
    for (int j2 = 0; j2 < 4; ++j2)
#pragma unroll
      for (int r = 0; r < 4; ++r)
        ao[((size_t)(b * 2048) + n0 + w * 16 + fg * 4 + r) * 768 + h * 64 + j2 * 16 + fr]
            = f2b(acc[j2][r] * il[r]);
    return;
  }

  // ---- att writer: barrier-free transpose-stream, bf16 slab ----
  const int idx = (bid - 768) * 4 + w;      // = b*4096 + n*2 + half
  const int b = idx >> 12;
  const int n = (idx >> 1) & 2047;
  const int half = idx & 1;
  const int hq = l >> 4, mg = l & 15;
  unsigned short* sl = smem + w * 1664;

  float iLv[3];
#pragma unroll
  for (int g = 0; g < 3; ++g)
    iLv[g] = iLst[((size_t)(b * 12 + g * 4 + hq)) * 2048 + n];

  for (int c = 0; c < 8; ++c) {
    const int m0 = half * 1024 + c * 128;
#pragma unroll
    for (int g = 0; g < 3; ++g) {
      int h = g * 4 + hq;
      bf8 pv = *(const bf8*)(Pws + ((size_t)(b * 12 + h) * 2048 + n) * 2048 + m0 + mg * 8);
      const unsigned short* pu = (const unsigned short*)&pv;
      // element (m, h) at sl[(m>>3)*104 + (m&7)*12 + h]; m = mg*8+j
#pragma unroll
      for (int j = 0; j < 8; ++j)
        sl[mg * 104 + j * 12 + h] = f2b(b2f(pu[j]) * iLv[g]);
    }
    // same-wave LDS RAW: compiler inserts lgkmcnt waits
    float* dst = att + (((size_t)(b * 2048 + n)) * 2048 + m0) * 12;
#pragma unroll
    for (int it = 0; it < 6; ++it) {
      int f = it * 256 + l * 4;
      int sa = (f / 96) * 104 + f % 96;
      ushort4 s4 = *(const ushort4*)&sl[sa];
      f4 v = {b2f(s4.x), b2f(s4.y), b2f(s4.z), b2f(s4.w)};
      *(f4*)(dst + f) = v;
    }
  }
}

extern "C" void kernel_launch(void* const* d_in, const int* in_sizes, int n_in,
                              void* d_out, int out_size, void* d_ws, size_t ws_size,
                              hipStream_t stream) {
  const float* x   = (const float*)d_in[0];
  const void*  msk = d_in[1];
  const float* Wq  = (const float*)d_in[2];
  const float* bq  = (const float*)d_in[3];
  const float* Wkv = (const float*)d_in[4];
  const float* bkv = (const float*)d_in[5];
  const float* Wp  = (const float*)d_in[6];
  const float* bp  = (const float*)d_in[7];
  float* out = (float*)d_out;
  float* att = out + (size_t)2 * 2048 * 768;

  char* ws = (char*)d_ws;
  float* maskbias = (float*)ws;                      // 4096 f32
  float* biasc    = maskbias + 4096;                 // 2304 f32
  unsigned short* xb  = (unsigned short*)(ws + 32768);
  unsigned short* Wct = xb  + (size_t)4096 * 768;    // [2304][768]
  unsigned short* Wpt = Wct + (size_t)2304 * 768;    // [768][768]
  unsigned short* qb  = Wpt + (size_t)768 * 768;     // [2][12][2048][64]
  unsigned short* kb  = qb  + (size_t)3145728;
  unsigned short* vTb = kb  + (size_t)3145728;       // [2][12][64][2048]
  float* iLstat = (float*)(vTb + (size_t)3145728);   // [24][2048]
  float* Lpart  = iLstat + 49152;                    // [24][32][2048] f32, 6.3MB
  unsigned short* Pws = (unsigned short*)(Lpart + (size_t)24 * 32 * 2048); // [24][2048][2048] bf16, 201MB
  unsigned short* ao = xb;                           // overlay: xb dead after k_gemm<0>

  k_prept<<<dim3(5401), dim3(256), 0, stream>>>(x, xb, msk, bq, bkv, maskbias, biasc,
                                                Wq, Wkv, Wp, Wct, Wpt);
  k_gemm<0><<<dim3(18, 32), dim3(256), 0, stream>>>(Wct, xb, biasc, nullptr, qb, kb, vTb, 768);
  k_pexp<<<dim3(16, 16, 24), dim3(256), 0, stream>>>(qb, kb, maskbias, Pws, Lpart);
  k_lred<<<dim3(192), dim3(256), 0, stream>>>(Lpart, iLstat);
  k_attwpv<<<dim3(2816), dim3(256), 0, stream>>>(Pws, iLstat, att, vTb, ao);
  k_gemm<1><<<dim3(6, 32), dim3(256), 0, stream>>>(Wpt, ao, bp, out, nullptr, nullptr, nullptr, 768);
}